// Round 1
// baseline (1374.555 us; speedup 1.0000x reference)
//
#include <hip/hip_runtime.h>

typedef float  floatx4  __attribute__((ext_vector_type(4)));
typedef __bf16 bf16x8   __attribute__((ext_vector_type(8)));
typedef unsigned short ushort8v __attribute__((ext_vector_type(8)));

constexpr int NB = 64;       // batch
constexpr int NT = 512;      // time
constexpr int DC = 4096, DD = 512, DM = 256, DTOT = 4864;
constexpr int RED = 128;
constexpr int MROWS = NB * NT;  // 32768

__device__ __forceinline__ unsigned short f2bf(float f) {
  unsigned u = __float_as_uint(f);
  unsigned r = u + 0x7FFFu + ((u >> 16) & 1u);   // RNE f32->bf16
  return (unsigned short)(r >> 16);
}

__device__ __forceinline__ ushort8v pack8(floatx4 a, floatx4 b) {
  ushort8v u;
  u[0] = f2bf(a[0]); u[1] = f2bf(a[1]); u[2] = f2bf(a[2]); u[3] = f2bf(a[3]);
  u[4] = f2bf(b[0]); u[5] = f2bf(b[1]); u[6] = f2bf(b[2]); u[7] = f2bf(b[3]);
  return u;
}

// C = A @ W^T + bias.  MODE 0: A = concat(content,distort,motion) [M,4864], W=fc0_w [128,4864]
//                      MODE 1: A = scores [M,128], W = stacked [wih_f;wih_b] [192,128]
// 64-row M tile per block, full N per block. bf16 MFMA 16x16x32, fp32 acc.
// A/W staged to LDS as bf16 with XOR-8 swizzle (k' = k ^ ((row&7)*8)).
template<int MODE>
__global__ __launch_bounds__(256, 2) void gemm_bt(
    const float* __restrict__ A0, const float* __restrict__ A1, const float* __restrict__ A2,
    const float* __restrict__ W0, const float* __restrict__ W1,
    const float* __restrict__ bias0, const float* __restrict__ bias1,
    float* __restrict__ outp)
{
  constexpr int BN   = (MODE == 0) ? 128 : 192;
  constexpr int KTOT = (MODE == 0) ? DTOT : RED;
  constexpr int WNT  = (MODE == 0) ? 2 : 3;   // n-tiles per wave (4 waves cover BN/16 tiles)

  __shared__ __align__(16) unsigned short As[64 * 64];
  __shared__ __align__(16) unsigned short Ws[BN * 64];

  const int tid  = threadIdx.x;
  const int lane = tid & 63;
  const int wave = tid >> 6;
  const int m0   = blockIdx.x * 64;

  floatx4 acc[4][WNT];
  #pragma unroll
  for (int mt = 0; mt < 4; ++mt)
    #pragma unroll
    for (int nt = 0; nt < WNT; ++nt)
      acc[mt][nt] = (floatx4){0.f, 0.f, 0.f, 0.f};

  const int lrow = lane & 15;
  const int lko  = (lane >> 4) * 8;

  for (int k0 = 0; k0 < KTOT; k0 += 64) {
    __syncthreads();
    // ---- stage A tile: 64 rows x 64 k ----
    #pragma unroll
    for (int g = tid; g < 64 * 8; g += 256) {
      const int row = g >> 3;
      const int kk  = (g & 7) * 8;
      const int m   = m0 + row;
      const float* src;
      if (MODE == 0) {
        const int k = k0 + kk;      // k-chunk never straddles concat boundaries (all %64==0)
        if (k < DC)           src = A0 + (size_t)m * DC + k;
        else if (k < DC + DD) src = A1 + (size_t)m * DD + (k - DC);
        else                  src = A2 + (size_t)m * DM + (k - DC - DD);
      } else {
        src = A0 + (size_t)m * RED + (k0 + kk);
      }
      floatx4 f0 = *(const floatx4*)(src);
      floatx4 f1 = *(const floatx4*)(src + 4);
      *(ushort8v*)&As[row * 64 + (kk ^ ((row & 7) * 8))] = pack8(f0, f1);
    }
    // ---- stage W tile: BN rows x 64 k ----
    #pragma unroll
    for (int g = tid; g < BN * 8; g += 256) {
      const int row = g >> 3;
      const int kk  = (g & 7) * 8;
      const float* src;
      if (MODE == 0) {
        src = W0 + (size_t)row * DTOT + (k0 + kk);
      } else {
        src = (row < 96) ? (W0 + (size_t)row * RED + (k0 + kk))
                         : (W1 + (size_t)(row - 96) * RED + (k0 + kk));
      }
      floatx4 f0 = *(const floatx4*)(src);
      floatx4 f1 = *(const floatx4*)(src + 4);
      *(ushort8v*)&Ws[row * 64 + (kk ^ ((row & 7) * 8))] = pack8(f0, f1);
    }
    __syncthreads();
    // ---- MFMA over the 64-k chunk ----
    #pragma unroll
    for (int kk = 0; kk < 64; kk += 32) {
      bf16x8 af[4];
      #pragma unroll
      for (int mt = 0; mt < 4; ++mt) {
        const int row = mt * 16 + lrow;
        af[mt] = __builtin_bit_cast(bf16x8,
            *(const ushort8v*)&As[row * 64 + ((kk + lko) ^ ((row & 7) * 8))]);
      }
      #pragma unroll
      for (int nt = 0; nt < WNT; ++nt) {
        const int wrow = (wave * WNT + nt) * 16 + lrow;
        bf16x8 wf = __builtin_bit_cast(bf16x8,
            *(const ushort8v*)&Ws[wrow * 64 + ((kk + lko) ^ ((wrow & 7) * 8))]);
        #pragma unroll
        for (int mt = 0; mt < 4; ++mt)
          acc[mt][nt] = __builtin_amdgcn_mfma_f32_16x16x32_bf16(af[mt], wf, acc[mt][nt], 0, 0, 0);
      }
    }
  }
  // ---- epilogue: C/D layout col=lane&15, row=(lane>>4)*4+r ----
  #pragma unroll
  for (int nt = 0; nt < WNT; ++nt) {
    const int n = (wave * WNT + nt) * 16 + lrow;
    const float bv = (MODE == 0) ? bias0[n]
                                 : ((n < 96) ? bias0[n] : bias1[n - 96]);
    #pragma unroll
    for (int mt = 0; mt < 4; ++mt) {
      const int mr = m0 + mt * 16 + (lane >> 4) * 4;
      #pragma unroll
      for (int r = 0; r < 4; ++r)
        outp[(size_t)(mr + r) * BN + n] = acc[mt][nt][r] + bv;
    }
  }
}

// One block per (batch, dir). 128 threads; thread g<96 owns gate g (r:0-31, z:32-63, n:64-95).
// Only steps t < vlen are run (masked tail is h-frozen and multiplied by maskf=0 downstream).
__global__ __launch_bounds__(128) void gru_kernel(
    const float* __restrict__ xg,
    const float* __restrict__ whh_f, const float* __restrict__ whh_b,
    const float* __restrict__ bhh_f, const float* __restrict__ bhh_b,
    const int* __restrict__ inputLength,
    float* __restrict__ outfb)
{
  const int b   = blockIdx.x >> 1;
  const int dir = blockIdx.x & 1;
  const int tid = threadIdx.x;
  const int vlen = inputLength[b] - 9;

  const float* whh = dir ? whh_b : whh_f;
  const float* bhh = dir ? bhh_b : bhh_f;

  __shared__ __align__(16) float h_lds[32];
  __shared__ float rz[64];

  float w[32];
  float bh = 0.f;
  if (tid < 96) {
    bh = bhh[tid];
    #pragma unroll
    for (int j = 0; j < 32; ++j) w[j] = whh[tid * 32 + j];
  } else {
    #pragma unroll
    for (int j = 0; j < 32; ++j) w[j] = 0.f;
  }
  if (tid < 32) h_lds[tid] = 0.f;
  __syncthreads();

  for (int t = 0; t < vlen; ++t) {
    const int time = dir ? (vlen - 1 - t) : t;
    const float* xr = xg + ((size_t)(b * NT + time)) * 192 + dir * 96;

    float hr[32];
    #pragma unroll
    for (int i = 0; i < 8; ++i)
      *(floatx4*)&hr[4 * i] = *(const floatx4*)&h_lds[4 * i];

    float pre = bh;
    #pragma unroll
    for (int j = 0; j < 32; ++j) pre += w[j] * hr[j];

    const float x = (tid < 96) ? xr[tid] : 0.f;

    if (tid < 64) rz[tid] = 1.f / (1.f + __expf(-(x + pre)));
    __syncthreads();

    if (tid >= 64 && tid < 96) {
      const int i = tid - 64;
      const float n = tanhf(x + rz[i] * pre);
      const float z = rz[32 + i];
      const float hn = (1.f - z) * n + z * hr[i];
      h_lds[i] = hn;
      outfb[((size_t)(b * NT + time)) * 64 + dir * 32 + i] = hn;
    }
    __syncthreads();
  }
}

// q[b,t] = outputs[b,t,:64] . q_w + q_b for t<vlen else 0  (outputs = [out_f|out_b] * maskf)
__global__ __launch_bounds__(256) void q_kernel(
    const float* __restrict__ outfb, const float* __restrict__ q_w,
    const float* __restrict__ q_b, const int* __restrict__ inputLength,
    float* __restrict__ qv)
{
  const int m = blockIdx.x * 256 + threadIdx.x;
  const int b = m >> 9, t = m & 511;
  const int vlen = inputLength[b] - 9;
  float acc = 0.f;
  if (t < vlen) {
    acc = q_b[0];
    const float* row = outfb + (size_t)m * 64;
    #pragma unroll
    for (int j = 0; j < 64; ++j) acc += row[j] * q_w[j];
  }
  qv[m] = acc;
}

// Per-batch: memory-MLP -> argmax tau; TP score for that tau only; mean over valid frames.
__global__ __launch_bounds__(64) void final_kernel(
    const float* __restrict__ qv, const float* __restrict__ outfb,
    const int* __restrict__ inputLength,
    const float* __restrict__ m1w, const float* __restrict__ m1b,
    const float* __restrict__ m2w, const float* __restrict__ m2b,
    float* __restrict__ fin)
{
  const int b = blockIdx.x;
  const int tid = threadIdx.x;
  const int vlen = inputLength[b] - 9;

  __shared__ float qs[NT];
  __shared__ float es[NT];
  __shared__ float h1[32];
  __shared__ int tau_s;

  for (int t = tid; t < vlen; t += 64) {
    const float v = qv[b * NT + t];
    qs[t] = v;
    es[t] = expf(-v);
  }

  if (tid < 32) {
    const float* hf = outfb + (size_t)(b * NT + (vlen - 1)) * 64;       // lastHidForward
    const float* hb = outfb + (size_t)(b * NT) * 64 + 32;               // lastHidBackward
    float a = m1b[tid];
    #pragma unroll
    for (int j = 0; j < 32; ++j) a += m1w[tid * 64 + j] * hf[j];
    #pragma unroll
    for (int j = 0; j < 32; ++j) a += m1w[tid * 64 + 32 + j] * hb[j];
    h1[tid] = fmaxf(a, 0.f);
  }
  __syncthreads();
  if (tid == 0) {
    float best = -3.4e38f; int bi = 0;
    for (int i = 0; i < 5; ++i) {
      float lg = m2b[i];
      for (int j = 0; j < 32; ++j) lg += m2w[i * 32 + j] * h1[j];
      if (lg > best) { best = lg; bi = i; }   // softmax is monotone; first-max like jnp.argmax
    }
    tau_s = 8 + 2 * bi;
  }
  __syncthreads();
  const int tau = tau_s;

  float partial = 0.f;
  for (int t = tid; t < vlen; t += 64) {
    float msum = 0.f, nsum = 0.f;
    const int kmax = (tau < vlen - t) ? tau : (vlen - t);   // w=0 beyond vlen
    for (int k = 0; k < kmax; ++k) { msum += qs[t + k] * es[t + k]; nsum += es[t + k]; }
    const float ratio = (nsum > 0.f) ? (msum / nsum) : 0.f;
    float l = 3.4e38f;
    const int kb = (tau <= t + 1) ? tau : (t + 1);          // inf-pad for t-k<0
    for (int k = 0; k < kb; ++k) l = fminf(l, qs[t - k]);
    partial += 0.5f * ratio + 0.5f * l;
  }
  #pragma unroll
  for (int off = 32; off > 0; off >>= 1)
    partial += __shfl_down(partial, off);
  if (tid == 0) fin[b] = partial / (float)vlen;
}

extern "C" void kernel_launch(void* const* d_in, const int* in_sizes, int n_in,
                              void* d_out, int out_size, void* d_ws, size_t ws_size,
                              hipStream_t stream)
{
  const float* motion  = (const float*)d_in[0];
  const float* content = (const float*)d_in[1];
  const float* distort = (const float*)d_in[2];
  const int*   ilen    = (const int*)d_in[3];
  const float* fc0_w = (const float*)d_in[4];
  const float* fc0_b = (const float*)d_in[5];
  const float* wih_f = (const float*)d_in[6];
  const float* whh_f = (const float*)d_in[7];
  const float* bih_f = (const float*)d_in[8];
  const float* bhh_f = (const float*)d_in[9];
  const float* wih_b = (const float*)d_in[10];
  const float* whh_b = (const float*)d_in[11];
  const float* bih_b = (const float*)d_in[12];
  const float* bhh_b = (const float*)d_in[13];
  const float* q_w  = (const float*)d_in[14];
  const float* q_b  = (const float*)d_in[15];
  const float* m1w  = (const float*)d_in[16];
  const float* m1b  = (const float*)d_in[17];
  const float* m2w  = (const float*)d_in[18];
  const float* m2b  = (const float*)d_in[19];

  // workspace layout (total ~48.1 MB)
  char* ws = (char*)d_ws;
  float* scores = (float*)(ws);                                            // 16 MB [32768,128]
  float* xg     = (float*)(ws + (size_t)MROWS * RED * 4);                  // 24 MB [32768,192]
  float* outfb  = (float*)(ws + (size_t)MROWS * (RED + 192) * 4);          //  8 MB [32768,64]
  float* qv     = (float*)(ws + (size_t)MROWS * (RED + 192 + 64) * 4);     // 128 KB [32768]

  gemm_bt<0><<<dim3(MROWS / 64), dim3(256), 0, stream>>>(
      content, distort, motion, fc0_w, nullptr, fc0_b, nullptr, scores);
  gemm_bt<1><<<dim3(MROWS / 64), dim3(256), 0, stream>>>(
      scores, nullptr, nullptr, wih_f, wih_b, bih_f, bih_b, xg);
  gru_kernel<<<dim3(NB * 2), dim3(128), 0, stream>>>(
      xg, whh_f, whh_b, bhh_f, bhh_b, ilen, outfb);
  q_kernel<<<dim3(MROWS / 256), dim3(256), 0, stream>>>(outfb, q_w, q_b, ilen, qv);
  final_kernel<<<dim3(NB), dim3(64), 0, stream>>>(
      qv, outfb, ilen, m1w, m1b, m2w, m2b, (float*)d_out);
}

// Round 2
// 1109.250 us; speedup vs baseline: 1.2392x; 1.2392x over previous
//
#include <hip/hip_runtime.h>

typedef float  floatx4  __attribute__((ext_vector_type(4)));
typedef __bf16 bf16x8   __attribute__((ext_vector_type(8)));
typedef unsigned short ushort8v __attribute__((ext_vector_type(8)));

constexpr int NB = 64;       // batch
constexpr int NT = 512;      // time
constexpr int DC = 4096, DD = 512, DM = 256, DTOT = 4864;
constexpr int RED = 128;
constexpr int MROWS = NB * NT;  // 32768

__device__ __forceinline__ unsigned short f2bf(float f) {
  unsigned u = __float_as_uint(f);
  unsigned r = u + 0x7FFFu + ((u >> 16) & 1u);   // RNE f32->bf16
  return (unsigned short)(r >> 16);
}

__device__ __forceinline__ ushort8v pack8(floatx4 a, floatx4 b) {
  ushort8v u;
  u[0] = f2bf(a[0]); u[1] = f2bf(a[1]); u[2] = f2bf(a[2]); u[3] = f2bf(a[3]);
  u[4] = f2bf(b[0]); u[5] = f2bf(b[1]); u[6] = f2bf(b[2]); u[7] = f2bf(b[3]);
  return u;
}

// C = A @ W^T + bias.  MODE 0: A = concat(content,distort,motion) [M,4864], W=fc0_w [128,4864]
//                      MODE 1: A = scores [M,128], W = stacked [wih_f;wih_b] [192,128]
// 64-row M tile, full N per block. bf16 MFMA 16x16x32, fp32 acc.
// Pipelined: chunk k+1 is register-prefetched during the MFMA phase of chunk k,
// so HBM latency overlaps compute instead of being barrier-drained per iteration.
// LDS swizzle: 128-wide rows, chunk' = chunk ^ (row&15) -> 16 rows hit 16 distinct
// 16B slots (2-way bank aliasing = free).
template<int MODE>
__global__ __launch_bounds__(256, 2) void gemm_bt(
    const float* __restrict__ A0, const float* __restrict__ A1, const float* __restrict__ A2,
    const float* __restrict__ W0, const float* __restrict__ W1,
    const float* __restrict__ bias0, const float* __restrict__ bias1,
    float* __restrict__ outp)
{
  constexpr int BN   = (MODE == 0) ? 128 : 192;
  constexpr int KTOT = (MODE == 0) ? DTOT : RED;
  constexpr int WNT  = (MODE == 0) ? 2 : 3;       // n-tiles per wave
  constexpr int BK   = 128;                       // k per LDS chunk
  constexpr int ACH  = 64 * (BK / 8) / 256;       // A 8-elem chunks per thread (4)
  constexpr int WCH  = BN * (BK / 8) / 256;       // W chunks per thread (8 / 12)

  __shared__ __align__(16) unsigned short As[64 * BK];
  __shared__ __align__(16) unsigned short Ws[BN * BK];

  const int tid  = threadIdx.x;
  const int lane = tid & 63;
  const int wave = tid >> 6;
  const int m0   = blockIdx.x * 64;

  floatx4 pa[2 * ACH], pw[2 * WCH];

  auto loadA = [&](int k0) {
    #pragma unroll
    for (int c = 0; c < ACH; ++c) {
      const int g   = c * 256 + tid;
      const int row = g >> 4;
      const int kk  = (g & 15) * 8;
      const int m   = m0 + row;
      const float* src;
      if (MODE == 0) {
        const int k = k0 + kk;   // 128-chunks never straddle concat boundaries (all %128==0)
        if (k < DC)           src = A0 + (size_t)m * DC + k;
        else if (k < DC + DD) src = A1 + (size_t)m * DD + (k - DC);
        else                  src = A2 + (size_t)m * DM + (k - DC - DD);
      } else {
        src = A0 + (size_t)m * RED + (k0 + kk);
      }
      pa[2 * c]     = *(const floatx4*)(src);
      pa[2 * c + 1] = *(const floatx4*)(src + 4);
    }
  };
  auto loadW = [&](int k0) {
    #pragma unroll
    for (int c = 0; c < WCH; ++c) {
      const int g   = c * 256 + tid;
      const int row = g >> 4;
      const int kk  = (g & 15) * 8;
      const float* src;
      if (MODE == 0) {
        src = W0 + (size_t)row * DTOT + (k0 + kk);
      } else {
        src = (row < 96) ? (W0 + (size_t)row * RED + (k0 + kk))
                         : (W1 + (size_t)(row - 96) * RED + (k0 + kk));
      }
      pw[2 * c]     = *(const floatx4*)(src);
      pw[2 * c + 1] = *(const floatx4*)(src + 4);
    }
  };
  auto storeA = [&]() {
    #pragma unroll
    for (int c = 0; c < ACH; ++c) {
      const int g   = c * 256 + tid;
      const int row = g >> 4;
      const int kk  = (g & 15) * 8;
      *(ushort8v*)&As[row * BK + (kk ^ ((row & 15) * 8))] = pack8(pa[2 * c], pa[2 * c + 1]);
    }
  };
  auto storeW = [&]() {
    #pragma unroll
    for (int c = 0; c < WCH; ++c) {
      const int g   = c * 256 + tid;
      const int row = g >> 4;
      const int kk  = (g & 15) * 8;
      *(ushort8v*)&Ws[row * BK + (kk ^ ((row & 15) * 8))] = pack8(pw[2 * c], pw[2 * c + 1]);
    }
  };

  floatx4 acc[4][WNT];
  #pragma unroll
  for (int mt = 0; mt < 4; ++mt)
    #pragma unroll
    for (int nt = 0; nt < WNT; ++nt)
      acc[mt][nt] = (floatx4){0.f, 0.f, 0.f, 0.f};

  const int lrow = lane & 15;
  const int lko  = (lane >> 4) * 8;

  loadA(0); loadW(0);

  for (int k0 = 0; k0 < KTOT; k0 += BK) {
    storeA(); storeW();
    __syncthreads();
    if (k0 + BK < KTOT) { loadA(k0 + BK); loadW(k0 + BK); }  // overlaps MFMA phase below
    #pragma unroll
    for (int kk = 0; kk < BK; kk += 32) {
      bf16x8 af[4];
      #pragma unroll
      for (int mt = 0; mt < 4; ++mt) {
        const int row = mt * 16 + lrow;
        af[mt] = __builtin_bit_cast(bf16x8,
            *(const ushort8v*)&As[row * BK + ((kk + lko) ^ ((row & 15) * 8))]);
      }
      #pragma unroll
      for (int nt = 0; nt < WNT; ++nt) {
        const int wrow = (wave * WNT + nt) * 16 + lrow;
        bf16x8 wf = __builtin_bit_cast(bf16x8,
            *(const ushort8v*)&Ws[wrow * BK + ((kk + lko) ^ ((wrow & 15) * 8))]);
        #pragma unroll
        for (int mt = 0; mt < 4; ++mt)
          acc[mt][nt] = __builtin_amdgcn_mfma_f32_16x16x32_bf16(af[mt], wf, acc[mt][nt], 0, 0, 0);
      }
    }
    __syncthreads();
  }

  // ---- epilogue: C/D layout col=lane&15, row=(lane>>4)*4+r ----
  #pragma unroll
  for (int nt = 0; nt < WNT; ++nt) {
    const int n = (wave * WNT + nt) * 16 + lrow;
    const float bv = (MODE == 0) ? bias0[n]
                                 : ((n < 96) ? bias0[n] : bias1[n - 96]);
    #pragma unroll
    for (int mt = 0; mt < 4; ++mt) {
      const int mr = m0 + mt * 16 + (lane >> 4) * 4;
      #pragma unroll
      for (int r = 0; r < 4; ++r)
        outp[(size_t)(mr + r) * BN + n] = acc[mt][nt][r] + bv;
    }
  }
}

// One block (=1 wave) per (batch, dir). Lane l<32 owns all three gates of h-row l:
// 96 FMA/step, zero barriers (h exchanged via LDS within the single wave).
__global__ __launch_bounds__(64) void gru_kernel(
    const float* __restrict__ xg,
    const float* __restrict__ whh_f, const float* __restrict__ whh_b,
    const float* __restrict__ bhh_f, const float* __restrict__ bhh_b,
    const int* __restrict__ inputLength,
    float* __restrict__ outfb)
{
  const int b   = blockIdx.x >> 1;
  const int dir = blockIdx.x & 1;
  const int l   = threadIdx.x;
  const int vlen = inputLength[b] - 9;

  const float* whh = dir ? whh_b : whh_f;
  const float* bhh = dir ? bhh_b : bhh_f;

  __shared__ __align__(16) float hsh[32];

  float wr[32], wz[32], wn[32];
  float br = 0.f, bz = 0.f, bn = 0.f;
  if (l < 32) {
    br = bhh[l]; bz = bhh[32 + l]; bn = bhh[64 + l];
    #pragma unroll
    for (int j = 0; j < 32; ++j) {
      wr[j] = whh[l * 32 + j];
      wz[j] = whh[(32 + l) * 32 + j];
      wn[j] = whh[(64 + l) * 32 + j];
    }
    hsh[l] = 0.f;
  } else {
    #pragma unroll
    for (int j = 0; j < 32; ++j) { wr[j] = 0.f; wz[j] = 0.f; wn[j] = 0.f; }
  }

  for (int t = 0; t < vlen; ++t) {
    const int time = dir ? (vlen - 1 - t) : t;
    const float* xr = xg + ((size_t)(b * NT + time)) * 192 + dir * 96;

    // issue x loads first; latency hides under the 96-FMA dot chain
    float xv_r = 0.f, xv_z = 0.f, xv_n = 0.f, hl = 0.f;
    if (l < 32) {
      xv_r = xr[l]; xv_z = xr[32 + l]; xv_n = xr[64 + l];
      hl = hsh[l];
    }

    float h[32];
    #pragma unroll
    for (int i = 0; i < 8; ++i)
      *(floatx4*)&h[4 * i] = *(const floatx4*)&hsh[4 * i];   // broadcast reads

    // 6 independent chains for ILP
    float pr0 = br, pr1 = 0.f, pz0 = bz, pz1 = 0.f, pn0 = bn, pn1 = 0.f;
    #pragma unroll
    for (int j = 0; j < 16; ++j) {
      pr0 += wr[j] * h[j];       pr1 += wr[16 + j] * h[16 + j];
      pz0 += wz[j] * h[j];       pz1 += wz[16 + j] * h[16 + j];
      pn0 += wn[j] * h[j];       pn1 += wn[16 + j] * h[16 + j];
    }

    if (l < 32) {
      const float r  = 1.f / (1.f + __expf(-(xv_r + pr0 + pr1)));
      const float z  = 1.f / (1.f + __expf(-(xv_z + pz0 + pz1)));
      const float n  = tanhf(xv_n + r * (pn0 + pn1));
      const float hn = (1.f - z) * n + z * hl;
      hsh[l] = hn;
      outfb[((size_t)(b * NT + time)) * 64 + dir * 32 + l] = hn;
    }
  }
}

// q[b,t] = outputs[b,t,:64] . q_w + q_b for t<vlen else 0  (outputs = [out_f|out_b] * maskf)
__global__ __launch_bounds__(256) void q_kernel(
    const float* __restrict__ outfb, const float* __restrict__ q_w,
    const float* __restrict__ q_b, const int* __restrict__ inputLength,
    float* __restrict__ qv)
{
  const int m = blockIdx.x * 256 + threadIdx.x;
  const int b = m >> 9, t = m & 511;
  const int vlen = inputLength[b] - 9;
  float acc = 0.f;
  if (t < vlen) {
    acc = q_b[0];
    const float* row = outfb + (size_t)m * 64;
    #pragma unroll
    for (int j = 0; j < 64; ++j) acc += row[j] * q_w[j];
  }
  qv[m] = acc;
}

// Per-batch: memory-MLP -> argmax tau; TP score for that tau only; mean over valid frames.
__global__ __launch_bounds__(64) void final_kernel(
    const float* __restrict__ qv, const float* __restrict__ outfb,
    const int* __restrict__ inputLength,
    const float* __restrict__ m1w, const float* __restrict__ m1b,
    const float* __restrict__ m2w, const float* __restrict__ m2b,
    float* __restrict__ fin)
{
  const int b = blockIdx.x;
  const int tid = threadIdx.x;
  const int vlen = inputLength[b] - 9;

  __shared__ float qs[NT];
  __shared__ float es[NT];
  __shared__ float h1[32];
  __shared__ int tau_s;

  for (int t = tid; t < vlen; t += 64) {
    const float v = qv[b * NT + t];
    qs[t] = v;
    es[t] = expf(-v);
  }

  if (tid < 32) {
    const float* hf = outfb + (size_t)(b * NT + (vlen - 1)) * 64;       // lastHidForward
    const float* hb = outfb + (size_t)(b * NT) * 64 + 32;               // lastHidBackward
    float a = m1b[tid];
    #pragma unroll
    for (int j = 0; j < 32; ++j) a += m1w[tid * 64 + j] * hf[j];
    #pragma unroll
    for (int j = 0; j < 32; ++j) a += m1w[tid * 64 + 32 + j] * hb[j];
    h1[tid] = fmaxf(a, 0.f);
  }
  __syncthreads();
  if (tid == 0) {
    float best = -3.4e38f; int bi = 0;
    for (int i = 0; i < 5; ++i) {
      float lg = m2b[i];
      for (int j = 0; j < 32; ++j) lg += m2w[i * 32 + j] * h1[j];
      if (lg > best) { best = lg; bi = i; }   // softmax is monotone; first-max like jnp.argmax
    }
    tau_s = 8 + 2 * bi;
  }
  __syncthreads();
  const int tau = tau_s;

  float partial = 0.f;
  for (int t = tid; t < vlen; t += 64) {
    float msum = 0.f, nsum = 0.f;
    const int kmax = (tau < vlen - t) ? tau : (vlen - t);   // w=0 beyond vlen
    for (int k = 0; k < kmax; ++k) { msum += qs[t + k] * es[t + k]; nsum += es[t + k]; }
    const float ratio = (nsum > 0.f) ? (msum / nsum) : 0.f;
    float l = 3.4e38f;
    const int kb = (tau <= t + 1) ? tau : (t + 1);          // inf-pad for t-k<0
    for (int k = 0; k < kb; ++k) l = fminf(l, qs[t - k]);
    partial += 0.5f * ratio + 0.5f * l;
  }
  #pragma unroll
  for (int off = 32; off > 0; off >>= 1)
    partial += __shfl_down(partial, off);
  if (tid == 0) fin[b] = partial / (float)vlen;
}

extern "C" void kernel_launch(void* const* d_in, const int* in_sizes, int n_in,
                              void* d_out, int out_size, void* d_ws, size_t ws_size,
                              hipStream_t stream)
{
  const float* motion  = (const float*)d_in[0];
  const float* content = (const float*)d_in[1];
  const float* distort = (const float*)d_in[2];
  const int*   ilen    = (const int*)d_in[3];
  const float* fc0_w = (const float*)d_in[4];
  const float* fc0_b = (const float*)d_in[5];
  const float* wih_f = (const float*)d_in[6];
  const float* whh_f = (const float*)d_in[7];
  const float* bih_f = (const float*)d_in[8];
  const float* bhh_f = (const float*)d_in[9];
  const float* wih_b = (const float*)d_in[10];
  const float* whh_b = (const float*)d_in[11];
  const float* bih_b = (const float*)d_in[12];
  const float* bhh_b = (const float*)d_in[13];
  const float* q_w  = (const float*)d_in[14];
  const float* q_b  = (const float*)d_in[15];
  const float* m1w  = (const float*)d_in[16];
  const float* m1b  = (const float*)d_in[17];
  const float* m2w  = (const float*)d_in[18];
  const float* m2b  = (const float*)d_in[19];

  // workspace layout (total ~48.1 MB)
  char* ws = (char*)d_ws;
  float* scores = (float*)(ws);                                            // 16 MB [32768,128]
  float* xg     = (float*)(ws + (size_t)MROWS * RED * 4);                  // 24 MB [32768,192]
  float* outfb  = (float*)(ws + (size_t)MROWS * (RED + 192) * 4);          //  8 MB [32768,64]
  float* qv     = (float*)(ws + (size_t)MROWS * (RED + 192 + 64) * 4);     // 128 KB [32768]

  gemm_bt<0><<<dim3(MROWS / 64), dim3(256), 0, stream>>>(
      content, distort, motion, fc0_w, nullptr, fc0_b, nullptr, scores);
  gemm_bt<1><<<dim3(MROWS / 64), dim3(256), 0, stream>>>(
      scores, nullptr, nullptr, wih_f, wih_b, bih_f, bih_b, xg);
  gru_kernel<<<dim3(NB * 2), dim3(64), 0, stream>>>(
      xg, whh_f, whh_b, bhh_f, bhh_b, ilen, outfb);
  q_kernel<<<dim3(MROWS / 256), dim3(256), 0, stream>>>(outfb, q_w, q_b, ilen, qv);
  final_kernel<<<dim3(NB), dim3(64), 0, stream>>>(
      qv, outfb, ilen, m1w, m1b, m2w, m2b, (float*)d_out);
}